// Round 16
// baseline (184.601 us; speedup 1.0000x reference)
//
#include <hip/hip_runtime.h>
#include <hip/hip_bf16.h>

// Problem constants
#define B_SZ   8
#define SEQ    2048
#define EMBD   300      // embedding dim == pool1 window/stride
#define C1     32
#define C2     128
#define K      5
#define P1LEN  1504     // pooled positions actually needed: conv2 l<1500, +K-1 -> 1504
#define CHUNK  20       // conv2 positions per block
#define NCHUNK 75       // 1500 / 20

// ---------------------------------------------------------------------------
// K1: embedding gather + conv1 (Cin=1) + bias + relu + maxpool(300) fused.
// block = (j, b): pool window j covers conv positions l in [300j, 300j+300),
// which reads h[300j .. 300j+304] = emb[x[b][j]][0..299] ++ emb[x[b][j+1]][0..4].
// 256 threads = 32 channels x 8 position-slices of 38.
// ---------------------------------------------------------------------------
__global__ __launch_bounds__(256) void k1_emb_conv_pool(
    const int* __restrict__ x, const float* __restrict__ emb,
    const float* __restrict__ w1, const float* __restrict__ b1,
    float* __restrict__ p1 /* [B][P1LEN][C1] */)
{
    __shared__ __align__(16) float hs[EMBD + K];   // 305
    __shared__ float w1s[C1 * K];                  // 160
    __shared__ float b1s[C1];

    const int j   = blockIdx.x;
    const int b   = blockIdx.y;
    const int tid = threadIdx.x;

    const int t0 = x[b * SEQ + j];
    const int t1 = x[b * SEQ + j + 1];
    const float* __restrict__ r0 = emb + (long)t0 * EMBD;
    const float* __restrict__ r1 = emb + (long)t1 * EMBD;

    // emb rows are 1200 B and 16B-aligned (300*4 % 16 == 0): float4 staging.
    // Overlapping guards: a thread may issue several independent staging loads.
    if (tid < 75) {
        reinterpret_cast<float4*>(hs)[tid] =
            reinterpret_cast<const float4*>(r0)[tid];
    }
    if (tid < K) hs[EMBD + tid] = r1[tid];          // tail: emb[x[j+1]][0..4]
    if (tid < C1 * K) w1s[tid] = w1[tid];           // ALL 160 weights (tid 0..159)
    if (tid < C1) b1s[tid] = b1[tid];
    __syncthreads();

    const int c = tid >> 3;          // channel 0..31
    const int s = tid & 7;           // position slice 0..7 (low 3 lane bits)

    const float wk0 = w1s[c * K + 0];
    const float wk1 = w1s[c * K + 1];
    const float wk2 = w1s[c * K + 2];
    const float wk3 = w1s[c * K + 3];
    const float wk4 = w1s[c * K + 4];
    const float bc  = b1s[c];

    const int l0 = s * 38;           // slices: 8*38=304 >= 300, guard l<300
    float mx = 0.0f;                 // relu floor: max(0, y) == relu'd max
    float h0 = hs[l0 + 0], h1 = hs[l0 + 1], h2 = hs[l0 + 2], h3 = hs[l0 + 3];
    #pragma unroll
    for (int i = 0; i < 38; ++i) {
        const int l = l0 + i;
        if (l < EMBD) {
            const float h4 = hs[l + 4];
            float y = fmaf(h0, wk0,
                      fmaf(h1, wk1,
                      fmaf(h2, wk2,
                      fmaf(h3, wk3,
                      fmaf(h4, wk4, bc)))));
            mx = fmaxf(mx, y);
            h0 = h1; h1 = h2; h2 = h3; h3 = h4;
        }
    }
    // reduce max over the 8 position slices (lanes differing in low 3 bits)
    mx = fmaxf(mx, __shfl_xor(mx, 1, 64));
    mx = fmaxf(mx, __shfl_xor(mx, 2, 64));
    mx = fmaxf(mx, __shfl_xor(mx, 4, 64));
    if (s == 0) p1[((long)b * P1LEN + j) * C1 + c] = mx;
}

// ---------------------------------------------------------------------------
// K2: conv2 (32->128, K=5) + bias + relu + partial max over a 20-position chunk.
// Only conv2 positions l<1500 feed the single pool2 output.
// block = (chunk, b); 256 threads = 128 channels x 2 slices of 10 positions.
// ---------------------------------------------------------------------------
__global__ __launch_bounds__(256) void k2_conv2_pool(
    const float* __restrict__ p1, const float* __restrict__ w2,
    const float* __restrict__ b2, float* __restrict__ pmax /* [B][NCHUNK][C2] */)
{
    __shared__ __align__(16) float p1s[(CHUNK + K - 1) * C1]; // 24*32=768, [pos][ci]

    const int ch  = blockIdx.x;
    const int b   = blockIdx.y;
    const int tid = threadIdx.x;

    // base is a multiple of 32 floats -> 128B aligned: float4 staging
    const long base = ((long)b * P1LEN + ch * CHUNK) * C1;
    if (tid < 192) {
        reinterpret_cast<float4*>(p1s)[tid] =
            reinterpret_cast<const float4*>(p1 + base)[tid];
    }
    __syncthreads();

    const int c = tid >> 1;          // out channel 0..127
    const int s = tid & 1;           // position slice 0..1 (10 each)
    const float* __restrict__ wc = w2 + (long)c * C1 * K;

    float acc[10];
    #pragma unroll
    for (int i = 0; i < 10; ++i) acc[i] = 0.0f;

    #pragma unroll 4
    for (int ci = 0; ci < C1; ++ci) {
        const float w0 = wc[ci * K + 0];
        const float w1v = wc[ci * K + 1];
        const float w2v = wc[ci * K + 2];
        const float w3v = wc[ci * K + 3];
        const float w4v = wc[ci * K + 4];
        const int pbase = s * 10;
        #pragma unroll
        for (int i = 0; i < 10; ++i) {
            const int p = pbase + i;
            float a = acc[i];
            a = fmaf(p1s[(p + 0) * C1 + ci], w0,  a);
            a = fmaf(p1s[(p + 1) * C1 + ci], w1v, a);
            a = fmaf(p1s[(p + 2) * C1 + ci], w2v, a);
            a = fmaf(p1s[(p + 3) * C1 + ci], w3v, a);
            a = fmaf(p1s[(p + 4) * C1 + ci], w4v, a);
            acc[i] = a;
        }
    }

    const float bc = b2[c];
    float mx = 0.0f;                 // relu floor
    #pragma unroll
    for (int i = 0; i < 10; ++i) mx = fmaxf(mx, acc[i] + bc);
    mx = fmaxf(mx, __shfl_xor(mx, 1, 64));
    if (s == 0) pmax[((long)b * NCHUNK + ch) * C2 + c] = mx;
}

// ---------------------------------------------------------------------------
// K3: reduce chunk maxes -> p2[8][128], linear 128->5 + bias, softmax. 1 block.
// ---------------------------------------------------------------------------
__global__ __launch_bounds__(256) void k3_reduce_linear_softmax(
    const float* __restrict__ pmax, const float* __restrict__ wl,
    const float* __restrict__ bl, float* __restrict__ out)
{
    __shared__ float p2s[B_SZ * C2];
    __shared__ float lg[B_SZ * 5];

    const int tid = threadIdx.x;

    for (int q = tid; q < B_SZ * C2; q += 256) {
        const int b = q >> 7, c = q & 127;
        const float* __restrict__ src = pmax + (long)b * NCHUNK * C2 + c;
        float m = 0.0f;
        #pragma unroll 5
        for (int chn = 0; chn < NCHUNK; ++chn) m = fmaxf(m, src[(long)chn * C2]);
        p2s[q] = m;
    }
    __syncthreads();

    if (tid < B_SZ * 5) {
        const int b = tid / 5, o = tid % 5;
        float acc = bl[o];
        const float* __restrict__ w = wl + o * C2;
        #pragma unroll 8
        for (int c2 = 0; c2 < C2; ++c2) acc = fmaf(p2s[b * C2 + c2], w[c2], acc);
        lg[b * 5 + o] = acc;
    }
    __syncthreads();

    if (tid < B_SZ * 5) {
        const int b = tid / 5, o = tid % 5;
        float mx = lg[b * 5 + 0];
        #pragma unroll
        for (int o2 = 1; o2 < 5; ++o2) mx = fmaxf(mx, lg[b * 5 + o2]);
        float sum = 0.0f;
        #pragma unroll
        for (int o2 = 0; o2 < 5; ++o2) sum += expf(lg[b * 5 + o2] - mx);
        out[b * 5 + o] = expf(lg[b * 5 + o] - mx) / sum;
    }
}

// ---------------------------------------------------------------------------
extern "C" void kernel_launch(void* const* d_in, const int* in_sizes, int n_in,
                              void* d_out, int out_size, void* d_ws, size_t ws_size,
                              hipStream_t stream) {
    const int*   x   = (const int*)  d_in[0];
    const float* emb = (const float*)d_in[1];
    const float* w1  = (const float*)d_in[2];
    const float* b1  = (const float*)d_in[3];
    const float* w2  = (const float*)d_in[4];
    const float* b2  = (const float*)d_in[5];
    const float* wl  = (const float*)d_in[6];
    const float* bl  = (const float*)d_in[7];
    float* out = (float*)d_out;

    float* p1   = (float*)d_ws;                       // 8*1504*32  = 385024 floats
    float* pmax = p1 + (long)B_SZ * P1LEN * C1;       // 8*75*128   =  76800 floats

    k1_emb_conv_pool<<<dim3(P1LEN, B_SZ), 256, 0, stream>>>(x, emb, w1, b1, p1);
    k2_conv2_pool<<<dim3(NCHUNK, B_SZ), 256, 0, stream>>>(p1, w2, b2, pmax);
    k3_reduce_linear_softmax<<<1, 256, 0, stream>>>(pmax, wl, bl, out);
}